// Round 12
// baseline (205.048 us; speedup 1.0000x reference)
//
#include <hip/hip_runtime.h>

// SSIM loss, fused. Input: enhanced, target fp32 [16,3,512,512]. Output: scalar fp32.
// V13 = V12 (row-chain, interleaved float4 LDS + XOR swizzle [0 conflicts],
// lgkm-only barriers, 4ch pk_fma, item8, two-kernel tail) + PREFETCH DEPTH 2:
// two register window sets (winA/winB); tile q consumes set q%2 and re-issues
// its loads for tile q+2, giving an issue->use gap of ~2 tile periods (>1600cy)
// to cover HBM-miss latency (~900cy) that depth-1 (~600cy) left exposed.

#define TILE_W 64
#define TILE_H 16
#define HALO 3
#define IN_H 22                      // TILE_H + 2*HALO
#define ROW_SLOTS 66                 // float4 slots/row; 264 words, 264%32=8
#define IMG_H 512
#define IMG_W 512
#define NPLANES 48                   // 16 * 3
#define NTX 8                        // x-tiles per row chain
#define SSIM_C1 1.0e-4f
#define SSIM_C2 9.0e-4f

static __device__ constexpr float G[7] = {
    0.03663284536f, 0.11128076166f, 0.21674531251f, 0.27068216094f,
    0.21674531251f, 0.11128076166f, 0.03663284536f};

struct Win16 {  // one tile's 16-float window per image, in registers
  float4 x[4];
  float4 y[4];
};

// Packed fp32 FMA: d.lo = fma(a.lo,b.lo,c.lo), d.hi = fma(a.hi,b.hi,c.hi).
__device__ __forceinline__ float2 pk_fma(const float2 a, const float2 b,
                                         const float2 c) {
  float2 d;
  asm("v_pk_fma_f32 %0, %1, %2, %3" : "=v"(d) : "v"(a), "v"(b), "v"(c));
  return d;
}

// Aligned float4 load with zero fill outside [0, IMG_W). col is a multiple of 4.
__device__ __forceinline__ float4 ld4z(const float* __restrict__ row, int col) {
  if (col >= 0 && col + 3 < IMG_W) {
    return *reinterpret_cast<const float4*>(row + col);
  }
  float4 v;
  v.x = ((unsigned)(col + 0) < IMG_W) ? row[col + 0] : 0.f;
  v.y = ((unsigned)(col + 1) < IMG_W) ? row[col + 1] : 0.f;
  v.z = ((unsigned)(col + 2) < IMG_W) ? row[col + 2] : 0.f;
  v.w = ((unsigned)(col + 3) < IMG_W) ? row[col + 3] : 0.f;
  return v;
}

// Barrier that keeps prefetch global loads in flight: wait LDS ops only.
__device__ __forceinline__ void lds_barrier() {
  __builtin_amdgcn_sched_barrier(0);
  asm volatile("s_waitcnt lgkmcnt(0)" ::: "memory");
  __builtin_amdgcn_s_barrier();
  __builtin_amdgcn_sched_barrier(0);
}

__global__ __launch_bounds__(256, 4) void ssim_row_kernel(
    const float* __restrict__ x, const float* __restrict__ y,
    float* __restrict__ partial) {
  // One float4 = (mu1, mu2, S, XY) per (row, swizzled col). 23,232 B.
  __shared__ __align__(16) float4 hbuf[IN_H][ROW_SLOTS];

  const int tid = threadIdx.x;
  const int ty = blockIdx.x;           // 32 tile-rows
  const int plane = blockIdx.y;        // 48 planes
  const float* __restrict__ xp = x + (size_t)plane * (IMG_H * IMG_W);
  const float* __restrict__ yp = y + (size_t)plane * (IMG_H * IMG_W);
  const int y0 = ty * TILE_H - HALO;
  const bool edge_y = (ty == 0) | (ty == 31);

  // h-pass item8: thread t<176 owns (row t>>3, 8-col group t&7).
  const int hr = tid >> 3;
  const int cg = tid & 7;
  const bool active = tid < IN_H * 8;  // 176
  const int gy = y0 + hr;

  Win16 winA, winB;  // two prefetch sets (depth-2 pipeline)

  // Issue global loads for tile tx into w.
  auto load_tile = [&](int tx, Win16& w) {
    const int bcol = tx * TILE_W + 8 * cg - 4;
    const bool edge = edge_y | (tx == 0) | (tx == NTX - 1);
    if (!edge) {
      const float* xr = xp + (size_t)gy * IMG_W + bcol;
      const float* yr = yp + (size_t)gy * IMG_W + bcol;
#pragma unroll
      for (int v = 0; v < 4; ++v) {
        w.x[v] = *reinterpret_cast<const float4*>(xr + 4 * v);
        w.y[v] = *reinterpret_cast<const float4*>(yr + 4 * v);
      }
    } else if ((unsigned)gy < IMG_H) {
      const float* xr = xp + (size_t)gy * IMG_W;
      const float* yr = yp + (size_t)gy * IMG_W;
#pragma unroll
      for (int v = 0; v < 4; ++v) {
        w.x[v] = ld4z(xr, bcol + 4 * v);
        w.y[v] = ld4z(yr, bcol + 4 * v);
      }
    } else {
      const float4 z = make_float4(0.f, 0.f, 0.f, 0.f);
#pragma unroll
      for (int v = 0; v < 4; ++v) { w.x[v] = z; w.y[v] = z; }
    }
  };

  // Horizontal 7-tap over a prefetched window. Write col C=8cg+j to slot
  // 8cg + (j^cg): byte offset (j<<4)^(cg<<4) off the group base. Start banks
  // within a 16-lane window: each bank hit 2x = optimal (measured: 0 conflicts).
  auto h_pass = [&](const Win16& w) {
    const float wx[16] = {w.x[0].x, w.x[0].y, w.x[0].z, w.x[0].w,
                          w.x[1].x, w.x[1].y, w.x[1].z, w.x[1].w,
                          w.x[2].x, w.x[2].y, w.x[2].z, w.x[2].w,
                          w.x[3].x, w.x[3].y, w.x[3].z, w.x[3].w};
    const float wy[16] = {w.y[0].x, w.y[0].y, w.y[0].z, w.y[0].w,
                          w.y[1].x, w.y[1].y, w.y[1].z, w.y[1].w,
                          w.y[2].x, w.y[2].y, w.y[2].z, w.y[2].w,
                          w.y[3].x, w.y[3].y, w.y[3].z, w.y[3].w};
    float2 A[8], B[8];
#pragma unroll
    for (int j = 0; j < 8; ++j) {
      A[j] = make_float2(0.f, 0.f);
      B[j] = make_float2(0.f, 0.f);
    }
#pragma unroll
    for (int wi = 1; wi < 15; ++wi) {
      const float xv = wx[wi];
      const float yv = wy[wi];
      const float2 xyp = make_float2(xv, yv);
      const float2 spp = make_float2(fmaf(xv, xv, yv * yv), xv * yv);
#pragma unroll
      for (int j = 0; j < 8; ++j) {
        const int k = wi - 1 - j;  // tap index for output col j
        if (k >= 0 && k < 7) {
          const float2 gk2 = make_float2(G[k], G[k]);
          A[j] = pk_fma(gk2, xyp, A[j]);
          B[j] = pk_fma(gk2, spp, B[j]);
        }
      }
    }
    char* wbase = reinterpret_cast<char*>(&hbuf[hr][cg * 8]);
    const int cgx = cg << 4;
#pragma unroll
    for (int j = 0; j < 8; ++j) {
      *reinterpret_cast<float4*>(wbase + ((j << 4) ^ cgx)) =
          make_float4(A[j].x, A[j].y, B[j].x, B[j].y);
    }
  };

  // Vertical 7-tap + SSIM map; thread = (col tid&63, 4 rows). One b128 per
  // input row delivers all 4 channels; slot(c) matches the writer's swizzle.
  const int c = tid & 63;
  const int slotc = c ^ ((c >> 3) & 7);
  const int r0 = (tid >> 6) * 4;
  auto v_pass = [&]() -> float {
    const float4* hb = &hbuf[r0][slotc];
    float2 M[4], S4[4];
#pragma unroll
    for (int t = 0; t < 4; ++t) {
      M[t] = make_float2(0.f, 0.f);
      S4[t] = make_float2(0.f, 0.f);
    }
#pragma unroll
    for (int j = 0; j < 10; ++j) {  // rows r0+j, immediate offsets j*1056B
      const float4 v = hb[j * ROW_SLOTS];
      const float2 mv = make_float2(v.x, v.y);
      const float2 sv = make_float2(v.z, v.w);
#pragma unroll
      for (int t = 0; t < 4; ++t) {
        const int k = j - t;  // tap index for output row r0+t
        if (k >= 0 && k < 7) {
          const float2 gk2 = make_float2(G[k], G[k]);
          M[t] = pk_fma(gk2, mv, M[t]);
          S4[t] = pk_fma(gk2, sv, S4[t]);
        }
      }
    }
    float a = 0.f;
#pragma unroll
    for (int t = 0; t < 4; ++t) {
      const float mu1 = M[t].x, mu2 = M[t].y;
      const float mu12 = mu1 * mu2;
      const float msq = fmaf(mu1, mu1, mu2 * mu2);  // mu1^2 + mu2^2
      const float sig12 = S4[t].y - mu12;
      const float sigsum = S4[t].x - msq;           // sigma1 + sigma2
      const float num = fmaf(2.f, mu12, SSIM_C1) * fmaf(2.f, sig12, SSIM_C2);
      const float den = (msq + SSIM_C1) * (sigsum + SSIM_C2);
      float r = __builtin_amdgcn_rcpf(den);  // den > 0 always
      r = r * fmaf(-den, r, 2.f);            // 1 Newton step, ~1 ulp
      a = fmaf(num, r, a);
    }
    return a;
  };

  float acc = 0.f;
  if (active) {
    load_tile(0, winA);   // depth-2 prologue
    load_tile(1, winB);
  }
  // Explicit two-phase pairs: tile q consumes its set and re-issues for q+2.
#pragma unroll
  for (int qp = 0; qp < NTX; qp += 2) {
    // ---- tile qp (set A) ----
    if (active) {
      h_pass(winA);
      if (qp + 2 < NTX) load_tile(qp + 2, winA);
    }
    lds_barrier();   // h-writes visible; prefetch loads stay in flight
    acc += v_pass();
    lds_barrier();   // v-reads done before next h-writes reuse the buffer
    // ---- tile qp+1 (set B) ----
    if (active) {
      h_pass(winB);
      if (qp + 3 < NTX) load_tile(qp + 3, winB);
    }
    lds_barrier();
    acc += v_pass();
    lds_barrier();
  }

  // Block reduction once per row-chain (8 tiles accumulated per thread).
#pragma unroll
  for (int off = 32; off > 0; off >>= 1) acc += __shfl_down(acc, off, 64);
  __shared__ float wsum[4];
  if ((tid & 63) == 0) wsum[tid >> 6] = acc;
  __syncthreads();
  if (tid == 0) {
    partial[(size_t)plane * 32 + ty] = wsum[0] + wsum[1] + wsum[2] + wsum[3];
  }
}

__global__ __launch_bounds__(1024) void ssim_reduce_kernel(
    const float* __restrict__ partial, int n, float* __restrict__ out) {
  float acc = 0.f;
  const int nv = n >> 2;  // n = 1536 -> 384 float4
  const float4* __restrict__ p4 = reinterpret_cast<const float4*>(partial);
  for (int i = threadIdx.x; i < nv; i += 1024) {
    const float4 v = p4[i];
    acc += (v.x + v.y) + (v.z + v.w);
  }
#pragma unroll
  for (int off = 32; off > 0; off >>= 1) acc += __shfl_down(acc, off, 64);
  __shared__ float wsum[16];
  if ((threadIdx.x & 63) == 0) wsum[threadIdx.x >> 6] = acc;
  __syncthreads();
  if (threadIdx.x == 0) {
    float s = 0.f;
#pragma unroll
    for (int w = 0; w < 16; ++w) s += wsum[w];
    out[0] = 1.f - s * (1.f / (float)(NPLANES * IMG_H * IMG_W));
  }
}

extern "C" void kernel_launch(void* const* d_in, const int* in_sizes, int n_in,
                              void* d_out, int out_size, void* d_ws, size_t ws_size,
                              hipStream_t stream) {
  const float* enhanced = (const float*)d_in[0];
  const float* target = (const float*)d_in[1];
  float* out = (float*)d_out;
  float* partial = (float*)d_ws;

  dim3 grid(IMG_H / TILE_H, NPLANES, 1);  // 32 x 48 = 1536 row-chain blocks
  dim3 block(256, 1, 1);
  ssim_row_kernel<<<grid, block, 0, stream>>>(enhanced, target, partial);

  const int nblocks = (IMG_H / TILE_H) * NPLANES;  // 1536
  ssim_reduce_kernel<<<1, 1024, 0, stream>>>(partial, nblocks, out);
}

// Round 13
// 167.600 us; speedup vs baseline: 1.2234x; 1.2234x over previous
//
#include <hip/hip_runtime.h>

// SSIM loss, fused. Input: enhanced, target fp32 [16,3,512,512]. Output: scalar fp32.
// V14 = V12 (row-chain, interleaved float4 LDS + XOR swizzle [0 conflicts],
// lgkm-only barriers, 4ch pk_fma, item8, two-kernel tail) + prefetch depth 2,
// SPILL-PROOF: 16 named float4 scalars (no structs/arrays/ref-params -- every
// prior aggregate went to scratch), h_pass by value, fully unrolled phases,
// launch_bounds (256,3) for allocator slack. Tile q consumes window set q%2
// and re-issues it for tile q+2: issue->use gap ~2 tile periods > HBM latency.

#define TILE_W 64
#define TILE_H 16
#define HALO 3
#define IN_H 22                      // TILE_H + 2*HALO
#define ROW_SLOTS 66                 // float4 slots/row; 264 words, 264%32=8
#define IMG_H 512
#define IMG_W 512
#define NPLANES 48                   // 16 * 3
#define NTX 8                        // x-tiles per row chain
#define SSIM_C1 1.0e-4f
#define SSIM_C2 9.0e-4f

static __device__ constexpr float G[7] = {
    0.03663284536f, 0.11128076166f, 0.21674531251f, 0.27068216094f,
    0.21674531251f, 0.11128076166f, 0.03663284536f};

// Packed fp32 FMA: d.lo = fma(a.lo,b.lo,c.lo), d.hi = fma(a.hi,b.hi,c.hi).
__device__ __forceinline__ float2 pk_fma(const float2 a, const float2 b,
                                         const float2 c) {
  float2 d;
  asm("v_pk_fma_f32 %0, %1, %2, %3" : "=v"(d) : "v"(a), "v"(b), "v"(c));
  return d;
}

// Aligned float4 load with zero fill outside [0, IMG_W). col is a multiple of 4.
__device__ __forceinline__ float4 ld4z(const float* __restrict__ row, int col) {
  if (col >= 0 && col + 3 < IMG_W) {
    return *reinterpret_cast<const float4*>(row + col);
  }
  float4 v;
  v.x = ((unsigned)(col + 0) < IMG_W) ? row[col + 0] : 0.f;
  v.y = ((unsigned)(col + 1) < IMG_W) ? row[col + 1] : 0.f;
  v.z = ((unsigned)(col + 2) < IMG_W) ? row[col + 2] : 0.f;
  v.w = ((unsigned)(col + 3) < IMG_W) ? row[col + 3] : 0.f;
  return v;
}

// Barrier that keeps prefetch global loads in flight: wait LDS ops only.
__device__ __forceinline__ void lds_barrier() {
  __builtin_amdgcn_sched_barrier(0);
  asm volatile("s_waitcnt lgkmcnt(0)" ::: "memory");
  __builtin_amdgcn_s_barrier();
  __builtin_amdgcn_sched_barrier(0);
}

// Horizontal 7-tap over one item8 window (by value -- keeps operands in VGPRs).
// Writes col C=8cg+j to slot 8cg+(j^cg): byte offset (j<<4)^cgx off the group
// base; 0 bank conflicts measured (V11/V12).
__device__ __forceinline__ void h_pass(float4 x0, float4 x1, float4 x2,
                                       float4 x3, float4 y0, float4 y1,
                                       float4 y2, float4 y3, char* wbase,
                                       int cgx) {
  const float wx[16] = {x0.x, x0.y, x0.z, x0.w, x1.x, x1.y, x1.z, x1.w,
                        x2.x, x2.y, x2.z, x2.w, x3.x, x3.y, x3.z, x3.w};
  const float wy[16] = {y0.x, y0.y, y0.z, y0.w, y1.x, y1.y, y1.z, y1.w,
                        y2.x, y2.y, y2.z, y2.w, y3.x, y3.y, y3.z, y3.w};
  float2 A[8], B[8];
#pragma unroll
  for (int j = 0; j < 8; ++j) {
    A[j] = make_float2(0.f, 0.f);
    B[j] = make_float2(0.f, 0.f);
  }
#pragma unroll
  for (int wi = 1; wi < 15; ++wi) {
    const float xv = wx[wi];
    const float yv = wy[wi];
    const float2 xyp = make_float2(xv, yv);
    const float2 spp = make_float2(fmaf(xv, xv, yv * yv), xv * yv);
#pragma unroll
    for (int j = 0; j < 8; ++j) {
      const int k = wi - 1 - j;  // tap index for output col j
      if (k >= 0 && k < 7) {
        const float2 gk2 = make_float2(G[k], G[k]);
        A[j] = pk_fma(gk2, xyp, A[j]);
        B[j] = pk_fma(gk2, spp, B[j]);
      }
    }
  }
#pragma unroll
  for (int j = 0; j < 8; ++j) {
    *reinterpret_cast<float4*>(wbase + ((j << 4) ^ cgx)) =
        make_float4(A[j].x, A[j].y, B[j].x, B[j].y);
  }
}

// Load one tile's item8 window into the named scalars of set S.
#define LOADT(S, tx)                                                        \
  do {                                                                      \
    const int bcol_ = (tx)*TILE_W + 8 * cg - 4;                             \
    const bool edge_ = edge_y | ((tx) == 0) | ((tx) == NTX - 1);            \
    if (!edge_) {                                                           \
      const float* xr_ = xp + (size_t)gy * IMG_W + bcol_;                   \
      const float* yr_ = yp + (size_t)gy * IMG_W + bcol_;                   \
      px##S##0 = *reinterpret_cast<const float4*>(xr_);                     \
      px##S##1 = *reinterpret_cast<const float4*>(xr_ + 4);                 \
      px##S##2 = *reinterpret_cast<const float4*>(xr_ + 8);                 \
      px##S##3 = *reinterpret_cast<const float4*>(xr_ + 12);                \
      py##S##0 = *reinterpret_cast<const float4*>(yr_);                     \
      py##S##1 = *reinterpret_cast<const float4*>(yr_ + 4);                 \
      py##S##2 = *reinterpret_cast<const float4*>(yr_ + 8);                 \
      py##S##3 = *reinterpret_cast<const float4*>(yr_ + 12);                \
    } else if ((unsigned)gy < IMG_H) {                                      \
      const float* xr_ = xp + (size_t)gy * IMG_W;                           \
      const float* yr_ = yp + (size_t)gy * IMG_W;                           \
      px##S##0 = ld4z(xr_, bcol_);                                          \
      px##S##1 = ld4z(xr_, bcol_ + 4);                                      \
      px##S##2 = ld4z(xr_, bcol_ + 8);                                      \
      px##S##3 = ld4z(xr_, bcol_ + 12);                                     \
      py##S##0 = ld4z(yr_, bcol_);                                          \
      py##S##1 = ld4z(yr_, bcol_ + 4);                                      \
      py##S##2 = ld4z(yr_, bcol_ + 8);                                      \
      py##S##3 = ld4z(yr_, bcol_ + 12);                                     \
    } else {                                                                \
      const float4 z_ = make_float4(0.f, 0.f, 0.f, 0.f);                    \
      px##S##0 = z_; px##S##1 = z_; px##S##2 = z_; px##S##3 = z_;           \
      py##S##0 = z_; py##S##1 = z_; py##S##2 = z_; py##S##3 = z_;           \
    }                                                                       \
  } while (0)

#define HP(S)                                                               \
  h_pass(px##S##0, px##S##1, px##S##2, px##S##3, py##S##0, py##S##1,        \
         py##S##2, py##S##3, wbase, cgx)

// One pipeline phase: consume set S, re-issue it for tile TNEXT (if any).
#define PHASE(S, TNEXT)                                                     \
  do {                                                                      \
    if (active) {                                                           \
      HP(S);                                                                \
      if ((TNEXT) < NTX) LOADT(S, TNEXT);                                   \
    }                                                                       \
    lds_barrier(); /* h-writes visible; prefetch loads stay in flight */    \
    acc += v_pass();                                                        \
    lds_barrier(); /* v-reads done before next h-writes reuse buffer */     \
  } while (0)

__global__ __launch_bounds__(256, 3) void ssim_row_kernel(
    const float* __restrict__ x, const float* __restrict__ y,
    float* __restrict__ partial) {
  // One float4 = (mu1, mu2, S, XY) per (row, swizzled col). 23,232 B.
  __shared__ __align__(16) float4 hbuf[IN_H][ROW_SLOTS];

  const int tid = threadIdx.x;
  const int ty = blockIdx.x;           // 32 tile-rows
  const int plane = blockIdx.y;        // 48 planes
  const float* __restrict__ xp = x + (size_t)plane * (IMG_H * IMG_W);
  const float* __restrict__ yp = y + (size_t)plane * (IMG_H * IMG_W);
  const int y0 = ty * TILE_H - HALO;
  const bool edge_y = (ty == 0) | (ty == 31);

  // h-pass item8: thread t<176 owns (row t>>3, 8-col group t&7).
  const int hr = tid >> 3;
  const int cg = tid & 7;
  const bool active = tid < IN_H * 8;  // 176
  const int gy = y0 + hr;
  char* wbase = reinterpret_cast<char*>(&hbuf[hr][cg * 8]);
  const int cgx = cg << 4;

  // Two prefetch window sets as flat named scalars (spill-proof).
  float4 pxA0, pxA1, pxA2, pxA3, pyA0, pyA1, pyA2, pyA3;
  float4 pxB0, pxB1, pxB2, pxB3, pyB0, pyB1, pyB2, pyB3;

  // Vertical 7-tap + SSIM map; thread = (col tid&63, 4 rows). One b128 per
  // input row delivers all 4 channels; slot(c) matches the writer's swizzle.
  const int c = tid & 63;
  const int slotc = c ^ ((c >> 3) & 7);
  const int r0 = (tid >> 6) * 4;
  auto v_pass = [&]() -> float {
    const float4* hb = &hbuf[r0][slotc];
    float2 M[4], S4[4];
#pragma unroll
    for (int t = 0; t < 4; ++t) {
      M[t] = make_float2(0.f, 0.f);
      S4[t] = make_float2(0.f, 0.f);
    }
#pragma unroll
    for (int j = 0; j < 10; ++j) {  // rows r0+j, immediate offsets j*1056B
      const float4 v = hb[j * ROW_SLOTS];
      const float2 mv = make_float2(v.x, v.y);
      const float2 sv = make_float2(v.z, v.w);
#pragma unroll
      for (int t = 0; t < 4; ++t) {
        const int k = j - t;  // tap index for output row r0+t
        if (k >= 0 && k < 7) {
          const float2 gk2 = make_float2(G[k], G[k]);
          M[t] = pk_fma(gk2, mv, M[t]);
          S4[t] = pk_fma(gk2, sv, S4[t]);
        }
      }
    }
    float a = 0.f;
#pragma unroll
    for (int t = 0; t < 4; ++t) {
      const float mu1 = M[t].x, mu2 = M[t].y;
      const float mu12 = mu1 * mu2;
      const float msq = fmaf(mu1, mu1, mu2 * mu2);  // mu1^2 + mu2^2
      const float sig12 = S4[t].y - mu12;
      const float sigsum = S4[t].x - msq;           // sigma1 + sigma2
      const float num = fmaf(2.f, mu12, SSIM_C1) * fmaf(2.f, sig12, SSIM_C2);
      const float den = (msq + SSIM_C1) * (sigsum + SSIM_C2);
      float r = __builtin_amdgcn_rcpf(den);  // den > 0 always
      r = r * fmaf(-den, r, 2.f);            // 1 Newton step, ~1 ulp
      a = fmaf(num, r, a);
    }
    return a;
  };

  float acc = 0.f;
  if (active) {
    LOADT(A, 0);  // depth-2 prologue
    LOADT(B, 1);
  }
  PHASE(A, 2);  // tile 0
  PHASE(B, 3);  // tile 1
  PHASE(A, 4);  // tile 2
  PHASE(B, 5);  // tile 3
  PHASE(A, 6);  // tile 4
  PHASE(B, 7);  // tile 5
  PHASE(A, 8);  // tile 6 (no reload)
  PHASE(B, 9);  // tile 7 (no reload)

  // Block reduction once per row-chain (8 tiles accumulated per thread).
#pragma unroll
  for (int off = 32; off > 0; off >>= 1) acc += __shfl_down(acc, off, 64);
  __shared__ float wsum[4];
  if ((tid & 63) == 0) wsum[tid >> 6] = acc;
  __syncthreads();
  if (tid == 0) {
    partial[(size_t)plane * 32 + ty] = wsum[0] + wsum[1] + wsum[2] + wsum[3];
  }
}

__global__ __launch_bounds__(1024) void ssim_reduce_kernel(
    const float* __restrict__ partial, int n, float* __restrict__ out) {
  float acc = 0.f;
  const int nv = n >> 2;  // n = 1536 -> 384 float4
  const float4* __restrict__ p4 = reinterpret_cast<const float4*>(partial);
  for (int i = threadIdx.x; i < nv; i += 1024) {
    const float4 v = p4[i];
    acc += (v.x + v.y) + (v.z + v.w);
  }
#pragma unroll
  for (int off = 32; off > 0; off >>= 1) acc += __shfl_down(acc, off, 64);
  __shared__ float wsum[16];
  if ((threadIdx.x & 63) == 0) wsum[threadIdx.x >> 6] = acc;
  __syncthreads();
  if (threadIdx.x == 0) {
    float s = 0.f;
#pragma unroll
    for (int w = 0; w < 16; ++w) s += wsum[w];
    out[0] = 1.f - s * (1.f / (float)(NPLANES * IMG_H * IMG_W));
  }
}

extern "C" void kernel_launch(void* const* d_in, const int* in_sizes, int n_in,
                              void* d_out, int out_size, void* d_ws, size_t ws_size,
                              hipStream_t stream) {
  const float* enhanced = (const float*)d_in[0];
  const float* target = (const float*)d_in[1];
  float* out = (float*)d_out;
  float* partial = (float*)d_ws;

  dim3 grid(IMG_H / TILE_H, NPLANES, 1);  // 32 x 48 = 1536 row-chain blocks
  dim3 block(256, 1, 1);
  ssim_row_kernel<<<grid, block, 0, stream>>>(enhanced, target, partial);

  const int nblocks = (IMG_H / TILE_H) * NPLANES;  // 1536
  ssim_reduce_kernel<<<1, 1024, 0, stream>>>(partial, nblocks, out);
}

// Round 14
// 167.541 us; speedup vs baseline: 1.2239x; 1.0004x over previous
//
#include <hip/hip_runtime.h>

// SSIM loss, fused. Input: enhanced, target fp32 [16,3,512,512]. Output: scalar fp32.
// V15 = double-buffered LDS (46.5 KB) + interleaved-float4 XOR-swizzle layout
// (0 conflicts, V11/V12) + depth-2 prefetch in flat named scalars (V14) + one
// lgkm-only barrier per tile (V8's verified schedule).
// KEY: the 46.5 KB LDS footprint caps blocks at 3/CU, so the allocator's
// LDS-implied occupancy target is 3 waves/SIMD -> VGPR budget ~170, which fits
// the ~130-VGPR depth-2 pipeline WITHOUT spilling (the 23 KB variants targeted
// 6 waves/SIMD -> 85 VGPR and spilled every depth-2 attempt).

#define TILE_W 64
#define TILE_H 16
#define HALO 3
#define IN_H 22                      // TILE_H + 2*HALO
#define ROW_SLOTS 66                 // float4 slots/row; 264 words, 264%32=8
#define IMG_H 512
#define IMG_W 512
#define NPLANES 48                   // 16 * 3
#define NTX 8                        // x-tiles per row chain
#define SSIM_C1 1.0e-4f
#define SSIM_C2 9.0e-4f

static __device__ constexpr float G[7] = {
    0.03663284536f, 0.11128076166f, 0.21674531251f, 0.27068216094f,
    0.21674531251f, 0.11128076166f, 0.03663284536f};

// Packed fp32 FMA: d.lo = fma(a.lo,b.lo,c.lo), d.hi = fma(a.hi,b.hi,c.hi).
__device__ __forceinline__ float2 pk_fma(const float2 a, const float2 b,
                                         const float2 c) {
  float2 d;
  asm("v_pk_fma_f32 %0, %1, %2, %3" : "=v"(d) : "v"(a), "v"(b), "v"(c));
  return d;
}

// Aligned float4 load with zero fill outside [0, IMG_W). col is a multiple of 4.
__device__ __forceinline__ float4 ld4z(const float* __restrict__ row, int col) {
  if (col >= 0 && col + 3 < IMG_W) {
    return *reinterpret_cast<const float4*>(row + col);
  }
  float4 v;
  v.x = ((unsigned)(col + 0) < IMG_W) ? row[col + 0] : 0.f;
  v.y = ((unsigned)(col + 1) < IMG_W) ? row[col + 1] : 0.f;
  v.z = ((unsigned)(col + 2) < IMG_W) ? row[col + 2] : 0.f;
  v.w = ((unsigned)(col + 3) < IMG_W) ? row[col + 3] : 0.f;
  return v;
}

// Barrier that keeps prefetch global loads in flight: wait LDS ops only.
__device__ __forceinline__ void lds_barrier() {
  __builtin_amdgcn_sched_barrier(0);
  asm volatile("s_waitcnt lgkmcnt(0)" ::: "memory");
  __builtin_amdgcn_s_barrier();
  __builtin_amdgcn_sched_barrier(0);
}

// Horizontal 7-tap over one item8 window (by value -- operands stay in VGPRs).
// Writes col C=8cg+j to slot 8cg+(j^cg): byte offset (j<<4)^cgx off the group
// base; 0 bank conflicts measured (V11/V12).
__device__ __forceinline__ void h_pass(float4 x0, float4 x1, float4 x2,
                                       float4 x3, float4 y0, float4 y1,
                                       float4 y2, float4 y3, char* wbase,
                                       int cgx) {
  const float wx[16] = {x0.x, x0.y, x0.z, x0.w, x1.x, x1.y, x1.z, x1.w,
                        x2.x, x2.y, x2.z, x2.w, x3.x, x3.y, x3.z, x3.w};
  const float wy[16] = {y0.x, y0.y, y0.z, y0.w, y1.x, y1.y, y1.z, y1.w,
                        y2.x, y2.y, y2.z, y2.w, y3.x, y3.y, y3.z, y3.w};
  float2 A[8], B[8];
#pragma unroll
  for (int j = 0; j < 8; ++j) {
    A[j] = make_float2(0.f, 0.f);
    B[j] = make_float2(0.f, 0.f);
  }
#pragma unroll
  for (int wi = 1; wi < 15; ++wi) {
    const float xv = wx[wi];
    const float yv = wy[wi];
    const float2 xyp = make_float2(xv, yv);
    const float2 spp = make_float2(fmaf(xv, xv, yv * yv), xv * yv);
#pragma unroll
    for (int j = 0; j < 8; ++j) {
      const int k = wi - 1 - j;  // tap index for output col j
      if (k >= 0 && k < 7) {
        const float2 gk2 = make_float2(G[k], G[k]);
        A[j] = pk_fma(gk2, xyp, A[j]);
        B[j] = pk_fma(gk2, spp, B[j]);
      }
    }
  }
#pragma unroll
  for (int j = 0; j < 8; ++j) {
    *reinterpret_cast<float4*>(wbase + ((j << 4) ^ cgx)) =
        make_float4(A[j].x, A[j].y, B[j].x, B[j].y);
  }
}

// Load one tile's item8 window into the named scalars of set S.
#define LOADT(S, tx)                                                        \
  do {                                                                      \
    const int bcol_ = (tx)*TILE_W + 8 * cg - 4;                             \
    const bool edge_ = edge_y | ((tx) == 0) | ((tx) == NTX - 1);            \
    if (!edge_) {                                                           \
      const float* xr_ = xp + (size_t)gy * IMG_W + bcol_;                   \
      const float* yr_ = yp + (size_t)gy * IMG_W + bcol_;                   \
      px##S##0 = *reinterpret_cast<const float4*>(xr_);                     \
      px##S##1 = *reinterpret_cast<const float4*>(xr_ + 4);                 \
      px##S##2 = *reinterpret_cast<const float4*>(xr_ + 8);                 \
      px##S##3 = *reinterpret_cast<const float4*>(xr_ + 12);                \
      py##S##0 = *reinterpret_cast<const float4*>(yr_);                     \
      py##S##1 = *reinterpret_cast<const float4*>(yr_ + 4);                 \
      py##S##2 = *reinterpret_cast<const float4*>(yr_ + 8);                 \
      py##S##3 = *reinterpret_cast<const float4*>(yr_ + 12);                \
    } else if ((unsigned)gy < IMG_H) {                                      \
      const float* xr_ = xp + (size_t)gy * IMG_W;                           \
      const float* yr_ = yp + (size_t)gy * IMG_W;                           \
      px##S##0 = ld4z(xr_, bcol_);                                          \
      px##S##1 = ld4z(xr_, bcol_ + 4);                                      \
      px##S##2 = ld4z(xr_, bcol_ + 8);                                      \
      px##S##3 = ld4z(xr_, bcol_ + 12);                                     \
      py##S##0 = ld4z(yr_, bcol_);                                          \
      py##S##1 = ld4z(yr_, bcol_ + 4);                                      \
      py##S##2 = ld4z(yr_, bcol_ + 8);                                      \
      py##S##3 = ld4z(yr_, bcol_ + 12);                                     \
    } else {                                                                \
      const float4 z_ = make_float4(0.f, 0.f, 0.f, 0.f);                    \
      px##S##0 = z_; px##S##1 = z_; px##S##2 = z_; px##S##3 = z_;           \
      py##S##0 = z_; py##S##1 = z_; py##S##2 = z_; py##S##3 = z_;           \
    }                                                                       \
  } while (0)

#define HP(S, WB)                                                           \
  h_pass(px##S##0, px##S##1, px##S##2, px##S##3, py##S##0, py##S##1,        \
         py##S##2, py##S##3, (WB), cgx)

// One pipeline phase: h-pass set S into buffer WB, re-issue S for tile TNEXT,
// single lgkm-only barrier, then v-pass over read base RB.
// Safety (V8 argument, absmax 0): a wave re-writing buffer b at tile q+2 has
// passed barrier q+1, which every wave reaches only after its v(b) at tile q.
#define PHASE(S, WB, RB, TNEXT)                                             \
  do {                                                                      \
    if (active) {                                                           \
      HP(S, WB);                                                            \
      if ((TNEXT) < NTX) LOADT(S, TNEXT);                                   \
    }                                                                       \
    lds_barrier(); /* h-writes visible; prefetch loads stay in flight */    \
    acc += v_pass(RB);                                                      \
  } while (0)

__global__ __launch_bounds__(256, 3) void ssim_row_kernel(
    const float* __restrict__ x, const float* __restrict__ y,
    float* __restrict__ partial) {
  // Double-buffered: one float4 = (mu1,mu2,S,XY) per (row, swizzled col).
  __shared__ __align__(16) float4 hbuf[2][IN_H][ROW_SLOTS];  // 46,464 B

  const int tid = threadIdx.x;
  const int ty = blockIdx.x;           // 32 tile-rows
  const int plane = blockIdx.y;        // 48 planes
  const float* __restrict__ xp = x + (size_t)plane * (IMG_H * IMG_W);
  const float* __restrict__ yp = y + (size_t)plane * (IMG_H * IMG_W);
  const int y0 = ty * TILE_H - HALO;
  const bool edge_y = (ty == 0) | (ty == 31);

  // h-pass item8: thread t<176 owns (row t>>3, 8-col group t&7).
  const int hr = tid >> 3;
  const int cg = tid & 7;
  const bool active = tid < IN_H * 8;  // 176
  const int gy = y0 + hr;
  char* wbase0 = reinterpret_cast<char*>(&hbuf[0][hr][cg * 8]);
  char* wbase1 = reinterpret_cast<char*>(&hbuf[1][hr][cg * 8]);
  const int cgx = cg << 4;

  // Two prefetch window sets as flat named scalars (spill-proof).
  float4 pxA0, pxA1, pxA2, pxA3, pyA0, pyA1, pyA2, pyA3;
  float4 pxB0, pxB1, pxB2, pxB3, pyB0, pyB1, pyB2, pyB3;

  // Vertical 7-tap + SSIM map; thread = (col tid&63, 4 rows). One b128 per
  // input row delivers all 4 channels; slot(c) matches the writer's swizzle.
  const int c = tid & 63;
  const int slotc = c ^ ((c >> 3) & 7);
  const int r0 = (tid >> 6) * 4;
  const float4* hb0 = &hbuf[0][r0][slotc];
  const float4* hb1 = &hbuf[1][r0][slotc];
  auto v_pass = [&](const float4* hb) -> float {
    float2 M[4], S4[4];
#pragma unroll
    for (int t = 0; t < 4; ++t) {
      M[t] = make_float2(0.f, 0.f);
      S4[t] = make_float2(0.f, 0.f);
    }
#pragma unroll
    for (int j = 0; j < 10; ++j) {  // rows r0+j, immediate offsets j*1056B
      const float4 v = hb[j * ROW_SLOTS];
      const float2 mv = make_float2(v.x, v.y);
      const float2 sv = make_float2(v.z, v.w);
#pragma unroll
      for (int t = 0; t < 4; ++t) {
        const int k = j - t;  // tap index for output row r0+t
        if (k >= 0 && k < 7) {
          const float2 gk2 = make_float2(G[k], G[k]);
          M[t] = pk_fma(gk2, mv, M[t]);
          S4[t] = pk_fma(gk2, sv, S4[t]);
        }
      }
    }
    float a = 0.f;
#pragma unroll
    for (int t = 0; t < 4; ++t) {
      const float mu1 = M[t].x, mu2 = M[t].y;
      const float mu12 = mu1 * mu2;
      const float msq = fmaf(mu1, mu1, mu2 * mu2);  // mu1^2 + mu2^2
      const float sig12 = S4[t].y - mu12;
      const float sigsum = S4[t].x - msq;           // sigma1 + sigma2
      const float num = fmaf(2.f, mu12, SSIM_C1) * fmaf(2.f, sig12, SSIM_C2);
      const float den = (msq + SSIM_C1) * (sigsum + SSIM_C2);
      float r = __builtin_amdgcn_rcpf(den);  // den > 0 always
      r = r * fmaf(-den, r, 2.f);            // 1 Newton step, ~1 ulp
      a = fmaf(num, r, a);
    }
    return a;
  };

  float acc = 0.f;
  if (active) {
    LOADT(A, 0);  // depth-2 prologue
    LOADT(B, 1);
  }
  PHASE(A, wbase0, hb0, 2);  // tile 0 -> buf 0
  PHASE(B, wbase1, hb1, 3);  // tile 1 -> buf 1
  PHASE(A, wbase0, hb0, 4);  // tile 2
  PHASE(B, wbase1, hb1, 5);  // tile 3
  PHASE(A, wbase0, hb0, 6);  // tile 4
  PHASE(B, wbase1, hb1, 7);  // tile 5
  PHASE(A, wbase0, hb0, 8);  // tile 6 (no reload)
  PHASE(B, wbase1, hb1, 9);  // tile 7 (no reload)

  // Block reduction once per row-chain (8 tiles accumulated per thread).
#pragma unroll
  for (int off = 32; off > 0; off >>= 1) acc += __shfl_down(acc, off, 64);
  __shared__ float wsum[4];
  if ((tid & 63) == 0) wsum[tid >> 6] = acc;
  __syncthreads();
  if (tid == 0) {
    partial[(size_t)plane * 32 + ty] = wsum[0] + wsum[1] + wsum[2] + wsum[3];
  }
}

__global__ __launch_bounds__(1024) void ssim_reduce_kernel(
    const float* __restrict__ partial, int n, float* __restrict__ out) {
  float acc = 0.f;
  const int nv = n >> 2;  // n = 1536 -> 384 float4
  const float4* __restrict__ p4 = reinterpret_cast<const float4*>(partial);
  for (int i = threadIdx.x; i < nv; i += 1024) {
    const float4 v = p4[i];
    acc += (v.x + v.y) + (v.z + v.w);
  }
#pragma unroll
  for (int off = 32; off > 0; off >>= 1) acc += __shfl_down(acc, off, 64);
  __shared__ float wsum[16];
  if ((threadIdx.x & 63) == 0) wsum[threadIdx.x >> 6] = acc;
  __syncthreads();
  if (threadIdx.x == 0) {
    float s = 0.f;
#pragma unroll
    for (int w = 0; w < 16; ++w) s += wsum[w];
    out[0] = 1.f - s * (1.f / (float)(NPLANES * IMG_H * IMG_W));
  }
}

extern "C" void kernel_launch(void* const* d_in, const int* in_sizes, int n_in,
                              void* d_out, int out_size, void* d_ws, size_t ws_size,
                              hipStream_t stream) {
  const float* enhanced = (const float*)d_in[0];
  const float* target = (const float*)d_in[1];
  float* out = (float*)d_out;
  float* partial = (float*)d_ws;

  dim3 grid(IMG_H / TILE_H, NPLANES, 1);  // 32 x 48 = 1536 row-chain blocks
  dim3 block(256, 1, 1);
  ssim_row_kernel<<<grid, block, 0, stream>>>(enhanced, target, partial);

  const int nblocks = (IMG_H / TILE_H) * NPLANES;  // 1536
  ssim_reduce_kernel<<<1, 1024, 0, stream>>>(partial, nblocks, out);
}

// Round 15
// 143.764 us; speedup vs baseline: 1.4263x; 1.1654x over previous
//
#include <hip/hip_runtime.h>

// SSIM loss, fused. Input: enhanced, target fp32 [16,3,512,512]. Output: scalar fp32.
// V17 = barrier-free wave-independent kernel. One wave = one 16x16 mini-tile:
// h-pass (44 items = 22 rows x 2 col-groups, one per lane) writes a private
// [22][17]-float4 LDS slice; v-pass (V12's verified code) reads it back.
// NO barriers in the compute path (wave DS pipe is in-order; lgkm fence only).
// 4 independent waves/block, 12288 blocks, 23.9 KB LDS -> 6 blocks/CU = 24
// mutually unsynchronized waves per CU: stalls interleave instead of
// converging at barriers (the correlated-stall hypothesis from R7-R14).
// Bank math: stride 68 words == 4 (mod 32) -> h-writes ~5.5/bank,
// v-reads exactly 8/bank = the 64-lane b128 minimum.

#define MT 16                        // mini-tile: 16 cols x 16 rows per wave
#define HALO 3
#define IN_H 22                      // MT + 2*HALO
#define SLOTS 17                     // float4 slots/row (16 + 1 pad)
#define IMG_H 512
#define IMG_W 512
#define NPLANES 48                   // 16 * 3
#define SSIM_C1 1.0e-4f
#define SSIM_C2 9.0e-4f

static __device__ constexpr float G[7] = {
    0.03663284536f, 0.11128076166f, 0.21674531251f, 0.27068216094f,
    0.21674531251f, 0.11128076166f, 0.03663284536f};

// Packed fp32 FMA: d.lo = fma(a.lo,b.lo,c.lo), d.hi = fma(a.hi,b.hi,c.hi).
__device__ __forceinline__ float2 pk_fma(const float2 a, const float2 b,
                                         const float2 c) {
  float2 d;
  asm("v_pk_fma_f32 %0, %1, %2, %3" : "=v"(d) : "v"(a), "v"(b), "v"(c));
  return d;
}

// Aligned float4 load with zero fill outside [0, IMG_W). col is a multiple of 4.
__device__ __forceinline__ float4 ld4z(const float* __restrict__ row, int col) {
  if (col >= 0 && col + 3 < IMG_W) {
    return *reinterpret_cast<const float4*>(row + col);
  }
  float4 v;
  v.x = ((unsigned)(col + 0) < IMG_W) ? row[col + 0] : 0.f;
  v.y = ((unsigned)(col + 1) < IMG_W) ? row[col + 1] : 0.f;
  v.z = ((unsigned)(col + 2) < IMG_W) ? row[col + 2] : 0.f;
  v.w = ((unsigned)(col + 3) < IMG_W) ? row[col + 3] : 0.f;
  return v;
}

__global__ __launch_bounds__(256, 4) void ssim_wave_kernel(
    const float* __restrict__ x, const float* __restrict__ y,
    float* __restrict__ partial) {
  // Per-wave private slice: one float4 = (mu1, mu2, S, XY) per (row, col).
  __shared__ __align__(16) float4 hbuf[4][IN_H][SLOTS];  // 23,936 B -> 6 blk/CU
  __shared__ float wsum[4];

  const int tid = threadIdx.x;
  const int wid = tid >> 6;
  const int lane = tid & 63;
  const int tx = blockIdx.x * 4 + wid;   // [0,32): 16-col strips
  const int ty = blockIdx.y;             // [0,32): 16-row strips
  const int plane = blockIdx.z;
  const float* __restrict__ xp = x + (size_t)plane * (IMG_H * IMG_W);
  const float* __restrict__ yp = y + (size_t)plane * (IMG_H * IMG_W);
  const int x0 = tx * MT;
  const int y0 = ty * MT - HALO;
  const bool edge = (tx == 0) | (tx == 31) | (ty == 0) | (ty == 31);
  float4(*mybuf)[SLOTS] = hbuf[wid];

  // ---- Horizontal 7-tap: one item per lane (44 items: row r, col-group cg).
  // Window = 16 floats [x0+8cg-4 .. +11]; output j (0..7) uses indices j+1..j+7;
  // written to mybuf[r][8cg+j] as (mu1, mu2, S=x^2+y^2-conv, XY).
  if (lane < IN_H * 2) {
    const int r = lane >> 1;
    const int cg = lane & 1;
    const int gy = y0 + r;
    const int bcol = x0 + 8 * cg - 4;
    float4 xv0, xv1, xv2, xv3, yv0, yv1, yv2, yv3;
    if (!edge) {
      const float* xr = xp + (size_t)gy * IMG_W + bcol;
      const float* yr = yp + (size_t)gy * IMG_W + bcol;
      xv0 = *reinterpret_cast<const float4*>(xr);
      xv1 = *reinterpret_cast<const float4*>(xr + 4);
      xv2 = *reinterpret_cast<const float4*>(xr + 8);
      xv3 = *reinterpret_cast<const float4*>(xr + 12);
      yv0 = *reinterpret_cast<const float4*>(yr);
      yv1 = *reinterpret_cast<const float4*>(yr + 4);
      yv2 = *reinterpret_cast<const float4*>(yr + 8);
      yv3 = *reinterpret_cast<const float4*>(yr + 12);
    } else if ((unsigned)gy < IMG_H) {
      const float* xr = xp + (size_t)gy * IMG_W;
      const float* yr = yp + (size_t)gy * IMG_W;
      xv0 = ld4z(xr, bcol);
      xv1 = ld4z(xr, bcol + 4);
      xv2 = ld4z(xr, bcol + 8);
      xv3 = ld4z(xr, bcol + 12);
      yv0 = ld4z(yr, bcol);
      yv1 = ld4z(yr, bcol + 4);
      yv2 = ld4z(yr, bcol + 8);
      yv3 = ld4z(yr, bcol + 12);
    } else {
      const float4 z = make_float4(0.f, 0.f, 0.f, 0.f);
      xv0 = xv1 = xv2 = xv3 = z;
      yv0 = yv1 = yv2 = yv3 = z;
    }
    const float wx[16] = {xv0.x, xv0.y, xv0.z, xv0.w, xv1.x, xv1.y, xv1.z,
                          xv1.w, xv2.x, xv2.y, xv2.z, xv2.w, xv3.x, xv3.y,
                          xv3.z, xv3.w};
    const float wy[16] = {yv0.x, yv0.y, yv0.z, yv0.w, yv1.x, yv1.y, yv1.z,
                          yv1.w, yv2.x, yv2.y, yv2.z, yv2.w, yv3.x, yv3.y,
                          yv3.z, yv3.w};
    float2 A[8], B[8];
#pragma unroll
    for (int j = 0; j < 8; ++j) {
      A[j] = make_float2(0.f, 0.f);
      B[j] = make_float2(0.f, 0.f);
    }
#pragma unroll
    for (int wi = 1; wi < 15; ++wi) {
      const float xv = wx[wi];
      const float yv = wy[wi];
      const float2 xyp = make_float2(xv, yv);
      const float2 spp = make_float2(fmaf(xv, xv, yv * yv), xv * yv);
#pragma unroll
      for (int j = 0; j < 8; ++j) {
        const int k = wi - 1 - j;  // tap index for output col j
        if (k >= 0 && k < 7) {
          const float2 gk2 = make_float2(G[k], G[k]);
          A[j] = pk_fma(gk2, xyp, A[j]);
          B[j] = pk_fma(gk2, spp, B[j]);
        }
      }
    }
#pragma unroll
    for (int j = 0; j < 8; ++j) {
      mybuf[r][8 * cg + j] = make_float4(A[j].x, A[j].y, B[j].x, B[j].y);
    }
  }

  // Wave-local write->read ordering: DS pipe is in-order per wave; fence the
  // compiler so v-reads are not scheduled above the writes' completion.
  __builtin_amdgcn_sched_barrier(0);
  asm volatile("s_waitcnt lgkmcnt(0)" ::: "memory");
  __builtin_amdgcn_sched_barrier(0);

  // ---- Vertical 7-tap + SSIM map: lane = (col c, 4-row group rg). ----
  const int c = lane & 15;
  const int rg = lane >> 4;  // rows 4rg..4rg+3
  float2 M[4], S4[4];
#pragma unroll
  for (int t = 0; t < 4; ++t) {
    M[t] = make_float2(0.f, 0.f);
    S4[t] = make_float2(0.f, 0.f);
  }
#pragma unroll
  for (int j = 0; j < 10; ++j) {  // input rows 4rg+j
    const float4 v = mybuf[4 * rg + j][c];
    const float2 mv = make_float2(v.x, v.y);
    const float2 sv = make_float2(v.z, v.w);
#pragma unroll
    for (int t = 0; t < 4; ++t) {
      const int k = j - t;  // tap index for output row 4rg+t
      if (k >= 0 && k < 7) {
        const float2 gk2 = make_float2(G[k], G[k]);
        M[t] = pk_fma(gk2, mv, M[t]);
        S4[t] = pk_fma(gk2, sv, S4[t]);
      }
    }
  }
  float acc = 0.f;
#pragma unroll
  for (int t = 0; t < 4; ++t) {
    const float mu1 = M[t].x, mu2 = M[t].y;
    const float mu12 = mu1 * mu2;
    const float msq = fmaf(mu1, mu1, mu2 * mu2);  // mu1^2 + mu2^2
    const float sig12 = S4[t].y - mu12;
    const float sigsum = S4[t].x - msq;           // sigma1 + sigma2
    const float num = fmaf(2.f, mu12, SSIM_C1) * fmaf(2.f, sig12, SSIM_C2);
    const float den = (msq + SSIM_C1) * (sigsum + SSIM_C2);
    float r = __builtin_amdgcn_rcpf(den);  // den > 0 always
    r = r * fmaf(-den, r, 2.f);            // 1 Newton step, ~1 ulp
    acc = fmaf(num, r, acc);
  }

  // Wave reduce, then one block combine (the only __syncthreads, at the end).
#pragma unroll
  for (int off = 32; off > 0; off >>= 1) acc += __shfl_down(acc, off, 64);
  if (lane == 0) wsum[wid] = acc;
  __syncthreads();
  if (tid == 0) {
    partial[((size_t)plane * 32 + ty) * 8 + blockIdx.x] =
        wsum[0] + wsum[1] + wsum[2] + wsum[3];
  }
}

__global__ __launch_bounds__(1024) void ssim_reduce_kernel(
    const float* __restrict__ partial, int n, float* __restrict__ out) {
  float acc = 0.f;
  const int nv = n >> 2;  // n = 12288 -> 3072 float4
  const float4* __restrict__ p4 = reinterpret_cast<const float4*>(partial);
  for (int i = threadIdx.x; i < nv; i += 1024) {
    const float4 v = p4[i];
    acc += (v.x + v.y) + (v.z + v.w);
  }
#pragma unroll
  for (int off = 32; off > 0; off >>= 1) acc += __shfl_down(acc, off, 64);
  __shared__ float wsum[16];
  if ((threadIdx.x & 63) == 0) wsum[threadIdx.x >> 6] = acc;
  __syncthreads();
  if (threadIdx.x == 0) {
    float s = 0.f;
#pragma unroll
    for (int w = 0; w < 16; ++w) s += wsum[w];
    out[0] = 1.f - s * (1.f / (float)(NPLANES * IMG_H * IMG_W));
  }
}

extern "C" void kernel_launch(void* const* d_in, const int* in_sizes, int n_in,
                              void* d_out, int out_size, void* d_ws, size_t ws_size,
                              hipStream_t stream) {
  const float* enhanced = (const float*)d_in[0];
  const float* target = (const float*)d_in[1];
  float* out = (float*)d_out;
  float* partial = (float*)d_ws;

  dim3 grid(8, 32, NPLANES);  // 8 x 32 x 48 = 12288 blocks (4 wave-tiles each)
  dim3 block(256, 1, 1);
  ssim_wave_kernel<<<grid, block, 0, stream>>>(enhanced, target, partial);

  const int nblocks = 8 * 32 * NPLANES;  // 12288
  ssim_reduce_kernel<<<1, 1024, 0, stream>>>(partial, nblocks, out);
}